// Round 1
// baseline (1493.791 us; speedup 1.0000x reference)
//
#include <hip/hip_runtime.h>
#include <math.h>

#define BB 64
#define LL 128
#define HH 1024
#define EE 512
#define VV 32000
#define MAXV 33000
#define KA 1536   // H+E

// ---------------- K0: build xa_T = [emb(tok) ; h] transposed, float4-grouped ----------------
// layout: xa4T[(k>>2)*256 + b*4 + (k&3)]
__global__ void k0_build_x(const int* __restrict__ tok, const float* __restrict__ hidden,
                           const float* __restrict__ emb, float* __restrict__ xa4T) {
    int idx = blockIdx.x * 256 + threadIdx.x;   // 1536*64 total
    int b = idx / KA, k = idx % KA;
    float v = (k < EE) ? emb[tok[b] * EE + k] : hidden[b * HH + (k - EE)];
    xa4T[(k >> 2) * 256 + b * 4 + (k & 3)] = v;
}

// ---------------- K1: attention logits a = xa @ attn_W.T + attn_b -> aT[l*64+b] ----------------
__global__ void k1_attn_logits(const float* __restrict__ xa4T, const float* __restrict__ attnW,
                               const float* __restrict__ attnb, float* __restrict__ aT) {
    int wave = (blockIdx.x * 256 + threadIdx.x) >> 6;  // 32 waves, 4 rows each
    int lane = threadIdx.x & 63;
    int r0 = wave * 4;
    float acc[4] = {0.f, 0.f, 0.f, 0.f};
    for (int k4 = 0; k4 < KA / 4; ++k4) {
        const float4 x = *(const float4*)&xa4T[k4 * 256 + lane * 4];
#pragma unroll
        for (int j = 0; j < 4; ++j) {
            const float4 w = *(const float4*)&attnW[(r0 + j) * KA + k4 * 4];
            acc[j] += x.x * w.x + x.y * w.y + x.z * w.z + x.w * w.w;
        }
    }
    for (int j = 0; j < 4; ++j) aT[(r0 + j) * 64 + lane] = acc[j] + attnb[r0 + j];
}

// ---------------- K2: per-batch softmax(a), sel, streaming pass over enc ----------------
__global__ __launch_bounds__(256) void k2_softmax_enc(
        const float* __restrict__ aT, const int* __restrict__ tok, const int* __restrict__ seq,
        const float* __restrict__ pprob, const float* __restrict__ enc,
        float* __restrict__ ap4T, float* __restrict__ gru4T, float* __restrict__ out3) {
    int b = blockIdx.x;
    int t = threadIdx.x;
    __shared__ float w[LL], selv[LL], red[256];
    float av = -1e30f;
    if (t < LL) av = aT[t * 64 + b];
    red[t] = av; __syncthreads();
    for (int s = 128; s > 0; s >>= 1) { if (t < s) red[t] = fmaxf(red[t], red[t + s]); __syncthreads(); }
    float m = red[0]; __syncthreads();
    float e = (t < LL) ? expf(av - m) : 0.f;
    red[t] = e; __syncthreads();
    for (int s = 128; s > 0; s >>= 1) { if (t < s) red[t] += red[t + s]; __syncthreads(); }
    float Z = red[0]; __syncthreads();
    if (t < LL) {
        float wv = e / Z;
        w[t] = wv;
        out3[b * LL + t] = wv;
        int tk = tok[b];
        selv[t] = (seq[b * LL + t] == tk) ? pprob[b * LL + t] : 0.f;
    }
    __syncthreads();
    float accA[4] = {0.f,0.f,0.f,0.f}, accS[4] = {0.f,0.f,0.f,0.f};
    const float* encb = enc + (size_t)b * LL * HH;
    for (int l = 0; l < LL; ++l) {
        float wl = w[l], sl = selv[l];
#pragma unroll
        for (int i = 0; i < 4; ++i) {
            float ev = encb[l * HH + t + i * 256];
            accA[i] += wl * ev;
            accS[i] += sl * truncf(ev);
        }
    }
#pragma unroll
    for (int i = 0; i < 4; ++i) {
        int h = t + i * 256;
        ap4T[(h >> 2) * 256 + b * 4 + (h & 3)] = accA[i];
        int h2 = HH + h;
        gru4T[(h2 >> 2) * 256 + b * 4 + (h2 & 3)] = accS[i];
    }
}

// ---------------- K3: out = relu([emb;attn_applied] @ comb_W.T + comb_b) -> gru4T[k<1024] ----------------
__global__ void k3_comb(const float* __restrict__ xa4T, const float* __restrict__ ap4T,
                        const float* __restrict__ combW, const float* __restrict__ combb,
                        float* __restrict__ gru4T) {
    int wave = (blockIdx.x * 256 + threadIdx.x) >> 6;  // 128 waves, 8 rows each
    int lane = threadIdx.x & 63;
    int r0 = wave * 8;
    float acc[8] = {0.f,0.f,0.f,0.f,0.f,0.f,0.f,0.f};
    for (int k4 = 0; k4 < 128; ++k4) {          // emb part k<512
        const float4 x = *(const float4*)&xa4T[k4 * 256 + lane * 4];
#pragma unroll
        for (int j = 0; j < 8; ++j) {
            const float4 w = *(const float4*)&combW[(r0 + j) * KA + k4 * 4];
            acc[j] += x.x * w.x + x.y * w.y + x.z * w.z + x.w * w.w;
        }
    }
    for (int k4 = 0; k4 < 256; ++k4) {          // attn_applied part
        const float4 x = *(const float4*)&ap4T[k4 * 256 + lane * 4];
#pragma unroll
        for (int j = 0; j < 8; ++j) {
            const float4 w = *(const float4*)&combW[(r0 + j) * KA + EE + k4 * 4];
            acc[j] += x.x * w.x + x.y * w.y + x.z * w.z + x.w * w.w;
        }
    }
    for (int j = 0; j < 8; ++j) {
        int r = r0 + j;
        float o = fmaxf(acc[j] + combb[r], 0.f);
        gru4T[(r >> 2) * 256 + lane * 4 + (r & 3)] = o;
    }
}

// ---------------- K4: gi = gru_in @ W_ih.T + b_ih ; gh = h @ W_hh.T + b_hh ----------------
__global__ void k4_gru_gemm(const float* __restrict__ gru4T, const float* __restrict__ h4T,
                            const float* __restrict__ Wih, const float* __restrict__ Whh,
                            const float* __restrict__ bih, const float* __restrict__ bhh,
                            float* __restrict__ giT, float* __restrict__ ghT) {
    int wave = (blockIdx.x * 256 + threadIdx.x) >> 6;  // 384 waves, 8 rows each
    int lane = threadIdx.x & 63;
    int r0 = wave * 8;
    float ai[8] = {0.f,0.f,0.f,0.f,0.f,0.f,0.f,0.f};
    float ah[8] = {0.f,0.f,0.f,0.f,0.f,0.f,0.f,0.f};
    for (int k4 = 0; k4 < 512; ++k4) {
        const float4 x = *(const float4*)&gru4T[k4 * 256 + lane * 4];
#pragma unroll
        for (int j = 0; j < 8; ++j) {
            const float4 w = *(const float4*)&Wih[(r0 + j) * 2048 + k4 * 4];
            ai[j] += x.x * w.x + x.y * w.y + x.z * w.z + x.w * w.w;
        }
    }
    for (int k4 = 0; k4 < 256; ++k4) {
        const float4 x = *(const float4*)&h4T[k4 * 256 + lane * 4];
#pragma unroll
        for (int j = 0; j < 8; ++j) {
            const float4 w = *(const float4*)&Whh[(r0 + j) * HH + k4 * 4];
            ah[j] += x.x * w.x + x.y * w.y + x.z * w.z + x.w * w.w;
        }
    }
    for (int j = 0; j < 8; ++j) {
        giT[(r0 + j) * 64 + lane] = ai[j] + bih[r0 + j];
        ghT[(r0 + j) * 64 + lane] = ah[j] + bhh[r0 + j];
    }
}

// ---------------- K5: GRU gates -> h_new ----------------
__global__ void k5_gates(const float* __restrict__ giT, const float* __restrict__ ghT,
                         const float* __restrict__ h4T, float* __restrict__ hn4T,
                         float* __restrict__ out2) {
    int idx = blockIdx.x * 256 + threadIdx.x;   // 65536
    int r = idx >> 6, b = idx & 63;
    float ir = giT[r * 64 + b], iz = giT[(HH + r) * 64 + b], in_ = giT[(2 * HH + r) * 64 + b];
    float hr = ghT[r * 64 + b], hz = ghT[(HH + r) * 64 + b], hn = ghT[(2 * HH + r) * 64 + b];
    float rr = 1.f / (1.f + expf(-(ir + hr)));
    float zz = 1.f / (1.f + expf(-(iz + hz)));
    float nn = tanhf(in_ + rr * hn);
    float hprev = h4T[(r >> 2) * 256 + b * 4 + (r & 3)];
    float hnew = (1.f - zz) * nn + zz * hprev;
    hn4T[(r >> 2) * 256 + b * 4 + (r & 3)] = hnew;
    out2[b * HH + r] = hnew;
}

// ---------------- K6: score_g = h_new @ Wo_W.T + Wo_b -> sgT[v*64+b] ----------------
__global__ __launch_bounds__(256) void k6_score_g(const float* __restrict__ hn4T,
                                                  const float* __restrict__ WoW,
                                                  const float* __restrict__ Wob,
                                                  float* __restrict__ sgT) {
    int wave = (blockIdx.x * 256 + threadIdx.x) >> 6;  // 2000 waves, 16 rows each
    int lane = threadIdx.x & 63;
    int r0 = wave * 16;
    float acc[16] = {0.f,0.f,0.f,0.f,0.f,0.f,0.f,0.f,0.f,0.f,0.f,0.f,0.f,0.f,0.f,0.f};
    for (int k4 = 0; k4 < 256; ++k4) {
        const float4 x = *(const float4*)&hn4T[k4 * 256 + lane * 4];
#pragma unroll
        for (int j = 0; j < 16; ++j) {
            const float4 w = *(const float4*)&WoW[(r0 + j) * HH + k4 * 4];
            acc[j] += x.x * w.x + x.y * w.y + x.z * w.z + x.w * w.w;
        }
    }
    for (int j = 0; j < 16; ++j) sgT[(r0 + j) * 64 + lane] = acc[j] + Wob[r0 + j];
}

// ---------------- K7: sc[b,l] = sum_n tanh((enc @ Wc_W.T)[b,l,n] + Wc_b[n]) * h_new[b,n] ----------------
// M-tile 32 rows, N-chunks of 128, K-tiles of 64. 256 blocks (8192/32).
__global__ __launch_bounds__(256) void k7_score_c(const float* __restrict__ enc,
                                                  const float* __restrict__ WcW,
                                                  const float* __restrict__ Wcb,
                                                  const float* __restrict__ hn4T,
                                                  float* __restrict__ sc) {
    __shared__ float As[64][36];    // [k][m], padded for b128 align + banks
    __shared__ float Ws[64][132];   // [k][n]
    __shared__ float rs[32];
    int t = threadIdx.x;
    int g0 = blockIdx.x * 32;
    int bb = g0 >> 7;               // uniform per block (32 | 128)
    int ty = t >> 5;                // 0..7 -> rows ty*4..+4
    int tx = t & 31;                // 0..31 -> cols tx*4..+4
    if (t < 32) rs[t] = 0.f;
    __syncthreads();
    for (int nc = 0; nc < 8; ++nc) {
        float acc[4][4] = {{0.f,0.f,0.f,0.f},{0.f,0.f,0.f,0.f},{0.f,0.f,0.f,0.f},{0.f,0.f,0.f,0.f}};
        for (int kt = 0; kt < 16; ++kt) {
            __syncthreads();
#pragma unroll
            for (int i = 0; i < 8; ++i) {        // A tile 32x64
                int e2 = t + i * 256;
                int m = e2 >> 6, k = e2 & 63;
                As[k][m] = enc[(size_t)(g0 + m) * HH + kt * 64 + k];
            }
#pragma unroll
            for (int i = 0; i < 32; ++i) {       // W tile 128x64
                int e2 = t + i * 256;
                int n = e2 >> 6, k = e2 & 63;
                Ws[k][n] = WcW[(size_t)(nc * 128 + n) * HH + kt * 64 + k];
            }
            __syncthreads();
#pragma unroll 8
            for (int k = 0; k < 64; ++k) {
                const float4 a4 = *(const float4*)&As[k][ty * 4];
                const float4 w4 = *(const float4*)&Ws[k][tx * 4];
                acc[0][0] += a4.x * w4.x; acc[0][1] += a4.x * w4.y; acc[0][2] += a4.x * w4.z; acc[0][3] += a4.x * w4.w;
                acc[1][0] += a4.y * w4.x; acc[1][1] += a4.y * w4.y; acc[1][2] += a4.y * w4.z; acc[1][3] += a4.y * w4.w;
                acc[2][0] += a4.z * w4.x; acc[2][1] += a4.z * w4.y; acc[2][2] += a4.z * w4.z; acc[2][3] += a4.z * w4.w;
                acc[3][0] += a4.w * w4.x; acc[3][1] += a4.w * w4.y; acc[3][2] += a4.w * w4.z; acc[3][3] += a4.w * w4.w;
            }
        }
        // epilogue: tanh(+bias) * h_new, reduce over the 4 local n, then across tx
        const float4 hb   = *(const float4*)&hn4T[(nc * 32 + tx) * 256 + bb * 4];
        const float4 bias = *(const float4*)&Wcb[nc * 128 + tx * 4];
#pragma unroll
        for (int mi = 0; mi < 4; ++mi) {
            float p = tanhf(acc[mi][0] + bias.x) * hb.x + tanhf(acc[mi][1] + bias.y) * hb.y
                    + tanhf(acc[mi][2] + bias.z) * hb.z + tanhf(acc[mi][3] + bias.w) * hb.w;
            p += __shfl_xor(p, 16); p += __shfl_xor(p, 8); p += __shfl_xor(p, 4);
            p += __shfl_xor(p, 2);  p += __shfl_xor(p, 1);
            if (tx == 0) atomicAdd(&rs[ty * 4 + mi], p);
        }
    }
    __syncthreads();
    if (t < 32) {
        int g = g0 + t;
        sc[(g >> 7) * LL + (g & 127)] = rs[t];
    }
}

// ---------------- F1: per-wave partial online max/sum over score_g ----------------
__global__ void f1_partial(const float* __restrict__ sgT, float* __restrict__ partM,
                           float* __restrict__ partS) {
    int wv = (blockIdx.x * 256 + threadIdx.x) >> 6;  // 128 waves x 250 v each
    int lane = threadIdx.x & 63;
    int v0 = wv * 250;
    float m = -1e30f, s = 0.f;
    for (int v = v0; v < v0 + 250; ++v) {
        float x = sgT[v * 64 + lane];
        float nm = fmaxf(m, x);
        s = s * expf(m - nm) + expf(x - nm);
        m = nm;
    }
    partM[wv * 64 + lane] = m;
    partS[wv * 64 + lane] = s;
}

// ---------------- F1b: combine partials + score_c -> M,Z ; write prob_c ----------------
__global__ void f1b_final(const float* __restrict__ partM, const float* __restrict__ partS,
                          const float* __restrict__ sc, float* __restrict__ Mb, float* __restrict__ Zb,
                          float* __restrict__ out4, float* __restrict__ pc) {
    int b = threadIdx.x;  // 64 threads
    float m = -1e30f, s = 0.f;
    for (int w = 0; w < 128; ++w) {
        float pm = partM[w * 64 + b], ps = partS[w * 64 + b];
        float nm = fmaxf(m, pm);
        s = s * expf(m - nm) + ps * expf(pm - nm);
        m = nm;
    }
    for (int l = 0; l < LL; ++l) {
        float x = sc[b * LL + l];
        float nm = fmaxf(m, x);
        s = s * expf(m - nm) + expf(x - nm);
        m = nm;
    }
    Mb[b] = m; Zb[b] = s;
    for (int l = 0; l < LL; ++l) {
        float p = expf(sc[b * LL + l] - m) / s;
        out4[b * LL + l] = p;
        pc[b * LL + l] = p;
    }
}

// ---------------- F2: expand prob_g into out1, zero the pad ----------------
__global__ void f2_expand(const float* __restrict__ sgT, const float* __restrict__ Mb,
                          const float* __restrict__ Zb, float* __restrict__ out1) {
    int b = blockIdx.y;
    int v = blockIdx.x * 256 + threadIdx.x;
    if (v >= MAXV) return;
    float val = 0.f;
    if (v < VV) val = expf(sgT[v * 64 + b] - Mb[b]) / Zb[b];
    out1[(size_t)b * MAXV + v] = val;
}

// ---------------- F3: scatter-add prob_c at input_seq positions ----------------
__global__ void f3_scatter(const int* __restrict__ seq, const float* __restrict__ pc,
                           float* __restrict__ out1) {
    int idx = blockIdx.x * 256 + threadIdx.x;  // 8192
    int b = idx >> 7, l = idx & 127;
    atomicAdd(&out1[(size_t)b * MAXV + seq[b * LL + l]], pc[b * LL + l]);
}

// ---------------- F4: finalize: zeros->1e-9, col2 = 1e-9, log ----------------
__global__ void f4_log(float* __restrict__ out1) {
    int b = blockIdx.y;
    int v = blockIdx.x * 256 + threadIdx.x;
    if (v >= MAXV) return;
    float val = out1[(size_t)b * MAXV + v];
    if (v == 2 || val == 0.f) val = 1e-9f;
    out1[(size_t)b * MAXV + v] = logf(val);
}

extern "C" void kernel_launch(void* const* d_in, const int* in_sizes, int n_in,
                              void* d_out, int out_size, void* d_ws, size_t ws_size,
                              hipStream_t stream) {
    (void)in_sizes; (void)n_in; (void)out_size; (void)ws_size;
    const int*   tok    = (const int*)  d_in[0];
    const float* hidden = (const float*)d_in[1];
    const float* enc    = (const float*)d_in[2];
    const int*   seq    = (const int*)  d_in[3];
    const float* pprob  = (const float*)d_in[4];
    const float* emb    = (const float*)d_in[5];
    const float* attnW  = (const float*)d_in[6];
    const float* attnb  = (const float*)d_in[7];
    const float* combW  = (const float*)d_in[8];
    const float* combb  = (const float*)d_in[9];
    const float* Wih    = (const float*)d_in[10];
    const float* Whh    = (const float*)d_in[11];
    const float* bih    = (const float*)d_in[12];
    const float* bhh    = (const float*)d_in[13];
    const float* WoW    = (const float*)d_in[14];
    const float* Wob    = (const float*)d_in[15];
    const float* WcW    = (const float*)d_in[16];
    const float* Wcb    = (const float*)d_in[17];

    float* out1 = (float*)d_out;
    float* out2 = out1 + (size_t)BB * MAXV;
    float* out3 = out2 + BB * HH;
    float* out4 = out3 + BB * LL;

    float* ws    = (float*)d_ws;
    float* xa4T  = ws;                 // 98304
    float* h4T   = xa4T + 128 * 256;   // alias: k>=512 slice
    float* aT    = ws + 98304;         // 8192
    float* ap4T  = ws + 106496;        // 65536
    float* gru4T = ws + 172032;        // 131072
    float* giT   = ws + 303104;        // 196608
    float* ghT   = ws + 499712;        // 196608
    float* hn4T  = ws + 696320;        // 65536
    float* sgT   = ws + 761856;        // 2048000
    float* sc    = ws + 2809856;       // 8192
    float* partM = ws + 2818048;       // 8192
    float* partS = ws + 2826240;       // 8192
    float* Mb    = ws + 2834432;       // 64
    float* Zb    = ws + 2834496;       // 64
    float* pc    = ws + 2834560;       // 8192  (total 2842752 floats = 11.4 MB)

    k0_build_x   <<<384, 256, 0, stream>>>(tok, hidden, emb, xa4T);
    k1_attn_logits<<<8, 256, 0, stream>>>(xa4T, attnW, attnb, aT);
    k2_softmax_enc<<<64, 256, 0, stream>>>(aT, tok, seq, pprob, enc, ap4T, gru4T, out3);
    k3_comb      <<<32, 256, 0, stream>>>(xa4T, ap4T, combW, combb, gru4T);
    k4_gru_gemm  <<<96, 256, 0, stream>>>(gru4T, h4T, Wih, Whh, bih, bhh, giT, ghT);
    k5_gates     <<<256, 256, 0, stream>>>(giT, ghT, h4T, hn4T, out2);
    k6_score_g   <<<500, 256, 0, stream>>>(hn4T, WoW, Wob, sgT);
    k7_score_c   <<<256, 256, 0, stream>>>(enc, WcW, Wcb, hn4T, sc);
    f1_partial   <<<32, 256, 0, stream>>>(sgT, partM, partS);
    f1b_final    <<<1, 64, 0, stream>>>(partM, partS, sc, Mb, Zb, out4, pc);
    f2_expand    <<<dim3(129, 64), 256, 0, stream>>>(sgT, Mb, Zb, out1);
    f3_scatter   <<<32, 256, 0, stream>>>(seq, pc, out1);
    f4_log       <<<dim3(129, 64), 256, 0, stream>>>(out1);
}

// Round 3
// 1171.861 us; speedup vs baseline: 1.2747x; 1.2747x over previous
//
#include <hip/hip_runtime.h>
#include <math.h>

#define BB 64
#define LL 128
#define HH 1024
#define EE 512
#define VV 32000
#define MAXV 33000

typedef float f32x4 __attribute__((ext_vector_type(4)));
typedef short bf16x8 __attribute__((ext_vector_type(8)));

__device__ __forceinline__ void gload_lds16(const void* g, void* l) {
    __builtin_amdgcn_global_load_lds((const __attribute__((address_space(1))) void*)g,
                                     (__attribute__((address_space(3))) void*)l, 16, 0, 0);
}

__device__ __forceinline__ unsigned short f2bf(float f) {
    unsigned u = __float_as_uint(f);
    return (unsigned short)((u + 0x7fffu + ((u >> 16) & 1u)) >> 16);
}

// ---------------- CVT: fp32 -> bf16 (RNE), vectorized ----------------
__global__ void cvt_bf16(const float* __restrict__ in, unsigned short* __restrict__ out, int n4) {
    int i = blockIdx.x * 256 + threadIdx.x;
    if (i >= n4) return;
    float4 v = ((const float4*)in)[i];
    ushort4 o;
    o.x = f2bf(v.x); o.y = f2bf(v.y); o.z = f2bf(v.z); o.w = f2bf(v.w);
    ((ushort4*)out)[i] = o;
}

// ---------------- K0: build xa4T = [emb(tok); h], layout [(k>>2)*256 + b*4 + (k&3)] ----------------
__global__ void k0_build_x(const int* __restrict__ tok, const float* __restrict__ hidden,
                           const float* __restrict__ emb, float* __restrict__ xa4T) {
    int idx = blockIdx.x * 256 + threadIdx.x;   // 1536*64
    int b = idx / 1536, k = idx % 1536;
    float v = (k < EE) ? emb[tok[b] * EE + k] : hidden[b * HH + (k - EE)];
    xa4T[(k >> 2) * 256 + b * 4 + (k & 3)] = v;
}

// ---------------- K0z: zero a contiguous region ----------------
__global__ void k0z_zero(float* __restrict__ p, int n) {
    int i = blockIdx.x * 256 + threadIdx.x;
    if (i < n) p[i] = 0.f;
}

// ---------------- generic GEMM: out[r][b] = sum_k W[r][k]*x[k][b] + bias[r] ----------------
// 64 rows/block, 4 waves x 16 rows, K tiled by 128, W staged in LDS via global_load_lds.
// x layout: [(k>>2)*256 + b*4 + (k&3)] (float4 per k-group per batch).
// OLAY 0: out[r*64+b]; OLAY 1: out[(r>>2)*256 + b*4 + (r&3)]. ACT 1: relu.
template <int ACT, int OLAY>
__global__ __launch_bounds__(256) void gemm64(const float* __restrict__ W,
        const float* __restrict__ bias, const float* __restrict__ xA,
        const float* __restrict__ xB, int K1, int K, float* __restrict__ out) {
    __shared__ __align__(16) float Ws[64 * 128];
    int tid = threadIdx.x, w = tid >> 6, lane = tid & 63;
    int r0 = blockIdx.x * 64;
    float acc[16];
#pragma unroll
    for (int j = 0; j < 16; ++j) acc[j] = 0.f;
    int nkt = K >> 7;
    for (int kt = 0; kt < nkt; ++kt) {
        __syncthreads();
        const float* Wbase = W + (size_t)r0 * K + kt * 128;
#pragma unroll
        for (int i = 0; i < 8; ++i) {
            int c = i * 256 + tid;           // 0..2047 chunks of 16B
            int row = c >> 5, kc = c & 31;
            gload_lds16(Wbase + (size_t)row * K + kc * 4, (char*)Ws + (i * 256 + w * 64) * 16);
        }
        asm volatile("s_waitcnt vmcnt(0)");
        __syncthreads();
        int kb = kt << 7;
        const float* xp = (kb < K1) ? (xA + (kb >> 2) * 256) : (xB + ((kb - K1) >> 2) * 256);
        const float* wr = &Ws[(w * 16) * 128];
#pragma unroll 4
        for (int k4 = 0; k4 < 32; ++k4) {
            float4 x4 = *(const float4*)&xp[k4 * 256 + lane * 4];
#pragma unroll
            for (int j = 0; j < 16; ++j) {
                float4 w4 = *(const float4*)&wr[j * 128 + k4 * 4];
                acc[j] += x4.x * w4.x + x4.y * w4.y + x4.z * w4.z + x4.w * w4.w;
            }
        }
    }
#pragma unroll
    for (int j = 0; j < 16; ++j) {
        int r = r0 + w * 16 + j;
        float v = acc[j] + bias[r];
        if (ACT == 1) v = fmaxf(v, 0.f);
        if (OLAY == 0) out[r * 64 + lane] = v;
        else out[(r >> 2) * 256 + lane * 4 + (r & 3)] = v;
    }
}

// ---------------- K2: softmax(a) + sel; stream enc over an L-chunk, atomic partials ----------------
__global__ __launch_bounds__(256) void k2_softmax_enc(
        const float* __restrict__ aT, const int* __restrict__ tok, const int* __restrict__ seq,
        const float* __restrict__ pprob, const float* __restrict__ enc,
        float* __restrict__ ap4T, float* __restrict__ gruSel, float* __restrict__ out3) {
    int b = blockIdx.x, lc = blockIdx.y, t = threadIdx.x;
    __shared__ float red[256];
    __shared__ float w_s[32], sel_s[32];
    float av = (t < LL) ? aT[t * 64 + b] : -1e30f;
    red[t] = av; __syncthreads();
    for (int s = 128; s > 0; s >>= 1) { if (t < s) red[t] = fmaxf(red[t], red[t + s]); __syncthreads(); }
    float m = red[0]; __syncthreads();
    float e = (t < LL) ? expf(av - m) : 0.f;
    red[t] = e; __syncthreads();
    for (int s = 128; s > 0; s >>= 1) { if (t < s) red[t] += red[t + s]; __syncthreads(); }
    float Z = red[0]; __syncthreads();
    if (t < LL) {
        float wv = e / Z;
        if (lc == 0) out3[b * LL + t] = wv;
        int l0 = lc * 32;
        if (t >= l0 && t < l0 + 32) {
            w_s[t - l0] = wv;
            sel_s[t - l0] = (seq[b * LL + t] == tok[b]) ? pprob[b * LL + t] : 0.f;
        }
    }
    __syncthreads();
    float accA[4] = {0.f,0.f,0.f,0.f}, accS[4] = {0.f,0.f,0.f,0.f};
    const float* encb = enc + (size_t)b * LL * HH + (size_t)lc * 32 * HH;
    for (int l = 0; l < 32; ++l) {
        float wl = w_s[l], sl = sel_s[l];
#pragma unroll
        for (int i = 0; i < 4; ++i) {
            float ev = encb[l * HH + t + i * 256];
            accA[i] += wl * ev;
            accS[i] += sl * truncf(ev);
        }
    }
#pragma unroll
    for (int i = 0; i < 4; ++i) {
        int h = t + i * 256;
        atomicAdd(&ap4T[(h >> 2) * 256 + b * 4 + (h & 3)], accA[i]);
        atomicAdd(&gruSel[(h >> 2) * 256 + b * 4 + (h & 3)], accS[i]);
    }
}

// ---------------- K5: GRU gates -> h_new ----------------
__global__ void k5_gates(const float* __restrict__ giT, const float* __restrict__ ghT,
                         const float* __restrict__ h4T, float* __restrict__ hn4T,
                         float* __restrict__ out2) {
    int idx = blockIdx.x * 256 + threadIdx.x;   // 65536
    int r = idx >> 6, b = idx & 63;
    float ir = giT[r * 64 + b], iz = giT[(HH + r) * 64 + b], in_ = giT[(2 * HH + r) * 64 + b];
    float hr = ghT[r * 64 + b], hz = ghT[(HH + r) * 64 + b], hn = ghT[(2 * HH + r) * 64 + b];
    float rr = 1.f / (1.f + expf(-(ir + hr)));
    float zz = 1.f / (1.f + expf(-(iz + hz)));
    float nn = tanhf(in_ + rr * hn);
    float hprev = h4T[(r >> 2) * 256 + b * 4 + (r & 3)];
    float hnew = (1.f - zz) * nn + zz * hprev;
    hn4T[(r >> 2) * 256 + b * 4 + (r & 3)] = hnew;
    out2[b * HH + r] = hnew;
}

// ---------------- K7: MFMA bf16 GEMM + fused tanh*h reduce -> sc (atomic) ----------------
// C[m][n] = sum_k enc[m][k]*WcW[n][k]; sc[m] += sum_n tanh(C+b[n])*h[b][n]
// 128x128 tile, BK=64, 4 waves (2x2), XOR-swizzled LDS (T2), pre-swizzled global src (rule 21).
__global__ __launch_bounds__(256) void k7_mfma(const unsigned short* __restrict__ encB,
        const unsigned short* __restrict__ WcB, const float* __restrict__ Wcb,
        const float* __restrict__ hn4T, float* __restrict__ sc) {
    __shared__ __align__(16) unsigned short As[128 * 64];
    __shared__ __align__(16) unsigned short Bs[128 * 64];
    __shared__ float h_s[128], bias_s[128];
    int tid = threadIdx.x, w = tid >> 6, lane = tid & 63;
    int wm = w >> 1, wn = w & 1;
    int mt = blockIdx.x >> 3, nt = blockIdx.x & 7;
    int m0 = mt * 128, n0 = nt * 128;
    if (tid < 128) {
        int n = n0 + tid;
        bias_s[tid] = Wcb[n];
        h_s[tid] = hn4T[(n >> 2) * 256 + mt * 4 + (n & 3)];
    }
    f32x4 acc[4][4];
#pragma unroll
    for (int mi = 0; mi < 4; ++mi)
#pragma unroll
        for (int ni = 0; ni < 4; ++ni) acc[mi][ni] = (f32x4){0.f, 0.f, 0.f, 0.f};

    for (int kt = 0; kt < 16; ++kt) {
        __syncthreads();
#pragma unroll
        for (int i = 0; i < 4; ++i) {       // A tile: 1024 chunks of 16B
            int c = i * 256 + tid;
            int row = c >> 3, cc = c & 7;
            int lc = cc ^ (row & 7);        // inverse-swizzled source (involution)
            gload_lds16(encB + (size_t)(m0 + row) * HH + kt * 64 + lc * 8,
                        (char*)As + (i * 256 + w * 64) * 16);
        }
#pragma unroll
        for (int i = 0; i < 4; ++i) {       // B tile
            int c = i * 256 + tid;
            int row = c >> 3, cc = c & 7;
            int lc = cc ^ (row & 7);
            gload_lds16(WcB + (size_t)(n0 + row) * HH + kt * 64 + lc * 8,
                        (char*)Bs + (i * 256 + w * 64) * 16);
        }
        asm volatile("s_waitcnt vmcnt(0)");
        __syncthreads();
#pragma unroll
        for (int ks = 0; ks < 2; ++ks) {
            bf16x8 af[4], bf[4];
#pragma unroll
            for (int mi = 0; mi < 4; ++mi) {
                int rr = wm * 64 + mi * 16 + (lane & 15);
                int lk = ks * 4 + (lane >> 4);
                af[mi] = *(const bf16x8*)((const char*)As + rr * 128 + ((lk ^ (rr & 7)) * 16));
            }
#pragma unroll
            for (int ni = 0; ni < 4; ++ni) {
                int rr = wn * 64 + ni * 16 + (lane & 15);
                int lk = ks * 4 + (lane >> 4);
                bf[ni] = *(const bf16x8*)((const char*)Bs + rr * 128 + ((lk ^ (rr & 7)) * 16));
            }
#pragma unroll
            for (int mi = 0; mi < 4; ++mi)
#pragma unroll
                for (int ni = 0; ni < 4; ++ni)
                    acc[mi][ni] = __builtin_amdgcn_mfma_f32_16x16x32_bf16(af[mi], bf[ni], acc[mi][ni], 0, 0, 0);
        }
    }
    // epilogue: rs[row] = sum_n tanh(acc + bias)*h
    float rs[16];
#pragma unroll
    for (int z = 0; z < 16; ++z) rs[z] = 0.f;
#pragma unroll
    for (int ni = 0; ni < 4; ++ni) {
        int nl = wn * 64 + ni * 16 + (lane & 15);
        float hv = h_s[nl], bv = bias_s[nl];
#pragma unroll
        for (int mi = 0; mi < 4; ++mi)
#pragma unroll
            for (int reg = 0; reg < 4; ++reg)
                rs[mi * 4 + reg] += tanhf(acc[mi][ni][reg] + bv) * hv;
    }
#pragma unroll
    for (int z = 0; z < 16; ++z) {
        float v = rs[z];
        v += __shfl_xor(v, 1); v += __shfl_xor(v, 2);
        v += __shfl_xor(v, 4); v += __shfl_xor(v, 8);
        rs[z] = v;
    }
    if ((lane & 15) == 0) {
        int g = lane >> 4;
#pragma unroll
        for (int mi = 0; mi < 4; ++mi)
#pragma unroll
            for (int reg = 0; reg < 4; ++reg)
                atomicAdd(&sc[mt * LL + wm * 64 + mi * 16 + g * 4 + reg], rs[mi * 4 + reg]);
    }
}

// ---------------- F1: per-wave partial online max/sum over score_g (500 waves) ----------------
__global__ void f1_partial(const float* __restrict__ sgT, float* __restrict__ partM,
                           float* __restrict__ partS) {
    int gid = blockIdx.x * 256 + threadIdx.x;
    int wv = gid >> 6, lane = gid & 63;
    int v0 = wv * 64;
    float m = -1e30f, s = 0.f;
    for (int v = v0; v < v0 + 64; ++v) {
        float x = sgT[v * 64 + lane];
        float nm = fmaxf(m, x);
        s = s * expf(m - nm) + expf(x - nm);
        m = nm;
    }
    partM[wv * 64 + lane] = m;
    partS[wv * 64 + lane] = s;
}

// ---------------- F1b: combine partials + score_c -> M,Z ; write prob_c ----------------
__global__ void f1b_final(const float* __restrict__ partM, const float* __restrict__ partS,
                          const float* __restrict__ sc, float* __restrict__ Mb, float* __restrict__ Zb,
                          float* __restrict__ out4, float* __restrict__ pc) {
    int b = threadIdx.x;  // 64 threads
    float m = -1e30f, s = 0.f;
    for (int w = 0; w < 500; ++w) {
        float pm = partM[w * 64 + b], ps = partS[w * 64 + b];
        float nm = fmaxf(m, pm);
        s = s * expf(m - nm) + ps * expf(pm - nm);
        m = nm;
    }
    for (int l = 0; l < LL; ++l) {
        float x = sc[b * LL + l];
        float nm = fmaxf(m, x);
        s = s * expf(m - nm) + expf(x - nm);
        m = nm;
    }
    Mb[b] = m; Zb[b] = s;
    for (int l = 0; l < LL; ++l) {
        float p = expf(sc[b * LL + l] - m) / s;
        out4[b * LL + l] = p;
        pc[b * LL + l] = p;
    }
}

// ---------------- F2: expand prob_g into out1 ----------------
__global__ void f2_expand(const float* __restrict__ sgT, const float* __restrict__ Mb,
                          const float* __restrict__ Zb, float* __restrict__ out1) {
    int b = blockIdx.y;
    int v = blockIdx.x * 256 + threadIdx.x;
    if (v >= MAXV) return;
    float val = 0.f;
    if (v < VV) val = expf(sgT[v * 64 + b] - Mb[b]) / Zb[b];
    out1[(size_t)b * MAXV + v] = val;
}

// ---------------- F3: scatter-add prob_c ----------------
__global__ void f3_scatter(const int* __restrict__ seq, const float* __restrict__ pc,
                           float* __restrict__ out1) {
    int idx = blockIdx.x * 256 + threadIdx.x;  // 8192
    int b = idx >> 7, l = idx & 127;
    atomicAdd(&out1[(size_t)b * MAXV + seq[b * LL + l]], pc[b * LL + l]);
}

// ---------------- F4: finalize + log ----------------
__global__ void f4_log(float* __restrict__ out1) {
    int b = blockIdx.y;
    int v = blockIdx.x * 256 + threadIdx.x;
    if (v >= MAXV) return;
    float val = out1[(size_t)b * MAXV + v];
    if (v == 2 || val == 0.f) val = 1e-9f;
    out1[(size_t)b * MAXV + v] = logf(val);
}

extern "C" void kernel_launch(void* const* d_in, const int* in_sizes, int n_in,
                              void* d_out, int out_size, void* d_ws, size_t ws_size,
                              hipStream_t stream) {
    (void)in_sizes; (void)n_in; (void)out_size; (void)ws_size;
    const int*   tok    = (const int*)  d_in[0];
    const float* hidden = (const float*)d_in[1];
    const float* enc    = (const float*)d_in[2];
    const int*   seq    = (const int*)  d_in[3];
    const float* pprob  = (const float*)d_in[4];
    const float* emb    = (const float*)d_in[5];
    const float* attnW  = (const float*)d_in[6];
    const float* attnb  = (const float*)d_in[7];
    const float* combW  = (const float*)d_in[8];
    const float* combb  = (const float*)d_in[9];
    const float* Wih    = (const float*)d_in[10];
    const float* Whh    = (const float*)d_in[11];
    const float* bih    = (const float*)d_in[12];
    const float* bhh    = (const float*)d_in[13];
    const float* WoW    = (const float*)d_in[14];
    const float* Wob    = (const float*)d_in[15];
    const float* WcW    = (const float*)d_in[16];
    const float* Wcb    = (const float*)d_in[17];

    float* out1 = (float*)d_out;
    float* out2 = out1 + (size_t)BB * MAXV;
    float* out3 = out2 + BB * HH;
    float* out4 = out3 + BB * LL;

    float* ws      = (float*)d_ws;
    float* xa4T    = ws;                    // 98304 (emb 512 + h 1024, 4T layout)
    float* h4T     = xa4T + 32768;          // h slice (k>=512)
    float* aT      = ws + 98304;            // 8192
    float* zeroReg = ws + 106496;           // zero region start
    float* ap4T    = ws + 106496;           // 65536
    float* gruSel  = ws + 172032;           // 65536
    float* sc      = ws + 237568;           // 8192   (zero region len 139264)
    float* gruOut  = ws + 245760;           // 65536
    float* giT     = ws + 311296;           // 196608 (3072*64)
    float* ghT     = ws + 507904;           // 196608 (3072*64)  -- FIXED size
    float* hn4T    = ws + 704512;           // 65536
    float* sgT     = ws + 770048;           // 2048000
    float* partM   = ws + 2818048;          // 32000
    float* partS   = ws + 2850048;          // 32000
    float* Mb      = ws + 2882048;          // 64
    float* Zb      = ws + 2882112;          // 64
    float* pc      = ws + 2882176;          // 8192 -> ends 2890368 floats
    unsigned short* encB = (unsigned short*)(ws + 2890368);   // 8388608 bf16
    unsigned short* WcB  = encB + 8388608;                    // 1048576 bf16

    cvt_bf16   <<<8192, 256, 0, stream>>>(enc, encB, 2097152);
    cvt_bf16   <<<1024, 256, 0, stream>>>(WcW, WcB, 262144);
    k0_build_x <<<384, 256, 0, stream>>>(tok, hidden, emb, xa4T);
    k0z_zero   <<<544, 256, 0, stream>>>(zeroReg, 139264);
    gemm64<0,0><<<2, 256, 0, stream>>>(attnW, attnb, xa4T, xa4T, 1536, 1536, aT);
    k2_softmax_enc<<<dim3(64, 4), 256, 0, stream>>>(aT, tok, seq, pprob, enc, ap4T, gruSel, out3);
    gemm64<1,1><<<16, 256, 0, stream>>>(combW, combb, xa4T, ap4T, 512, 1536, gruOut);
    gemm64<0,0><<<48, 256, 0, stream>>>(Wih, bih, gruOut, gruSel, 1024, 2048, giT);
    gemm64<0,0><<<48, 256, 0, stream>>>(Whh, bhh, h4T, h4T, 1024, 1024, ghT);   // FIXED: 3072 rows
    k5_gates   <<<256, 256, 0, stream>>>(giT, ghT, h4T, hn4T, out2);
    gemm64<0,0><<<500, 256, 0, stream>>>(WoW, Wob, hn4T, hn4T, 1024, 1024, sgT);
    k7_mfma    <<<512, 256, 0, stream>>>(encB, WcB, Wcb, hn4T, sc);
    f1_partial <<<125, 256, 0, stream>>>(sgT, partM, partS);
    f1b_final  <<<1, 64, 0, stream>>>(partM, partS, sc, Mb, Zb, out4, pc);
    f2_expand  <<<dim3(129, 64), 256, 0, stream>>>(sgT, Mb, Zb, out1);
    f3_scatter <<<32, 256, 0, stream>>>(seq, pc, out1);
    f4_log     <<<dim3(129, 64), 256, 0, stream>>>(out1);
}